// Round 2
// baseline (774.388 us; speedup 1.0000x reference)
//
#include <hip/hip_runtime.h>
#include <math.h>

#define N_NODES   15000
#define N_EDGES   60000
#define EVOCAB    54
#define NODE_INDIM 64
#define EDGE_INDIM 32
#define H  32
#define EH 64
#define N_BOND 4

// ---- phase-0 task layout (segment bases 64-aligned where lane math matters) ----
#define TASK_VOCAB (EVOCAB * 1024)                 // 55296
#define TASK_PROJ  (N_NODES * H)                   // 480000
#define TASK_PACK  (H * H)                         // 1024
#define TASK_DEG_BASE (TASK_VOCAB + TASK_PROJ + TASK_PACK)   // 536320
#define PH0_TOTAL  (TASK_DEG_BASE + N_EDGES)                 // 596320

// ---- workspace offsets (bytes) ----
#define WT_OFF  0          // 221184 B
#define H0_OFF  221184     // 1920000 B
#define H1_OFF  2141184    // 1920000 B
#define EPK_OFF 4061184    // 240000 B
#define W4_OFF  4301184    // 16384 B
#define W2_OFF  4317568    // 8192 B
#define RS_OFF  4325760    // 60000 B
#define BAR_OFF 4385760    // 4096 B   (zeroed together with rs: 64096 B)

// ===========================================================================
// Two-level grid barrier (monotonic counters, zeroed host-side per launch).
// bar layout (ints): sub[32] strided 16 ints (64B lines) | root @512 | flag @528
// Leaders: fence -> add sub; sub-finisher adds root; root-finisher sets flag;
// all spin on flag with relaxed agent loads + s_sleep, then fence.
// ===========================================================================
#define NSUB 32
__device__ __forceinline__ void gbar(int* __restrict__ bar, int ep, int subsz) {
    __syncthreads();
    if (threadIdx.x == 0) {
        __threadfence();                                   // release: wb L2
        int* sc = bar + ((blockIdx.x & (NSUB - 1)) << 4);
        int r = __hip_atomic_fetch_add(sc, 1, __ATOMIC_RELAXED, __HIP_MEMORY_SCOPE_AGENT);
        if (r + 1 == ep * subsz) {
            int r2 = __hip_atomic_fetch_add(bar + 512, 1, __ATOMIC_RELAXED, __HIP_MEMORY_SCOPE_AGENT);
            if (r2 + 1 == ep * NSUB) {
                __hip_atomic_store(bar + 528, ep, __ATOMIC_RELAXED, __HIP_MEMORY_SCOPE_AGENT);
            }
        }
        while (__hip_atomic_load(bar + 528, __ATOMIC_RELAXED, __HIP_MEMORY_SCOPE_AGENT) < ep)
            __builtin_amdgcn_s_sleep(1);
        __threadfence();                                   // acquire: inv L1/L2
    }
    __syncthreads();
}

// ===========================================================================
// Cooperative mega-kernel, custom barriers (5 total):
//  P0: vocab Wt | h0 proj | GRU pack | degree count (rs zeroed host-side)
//  b1 | P1: scan (block 0) | b2 | P2: scatter | b3 | step0 | b4 | step1 | b5 | step2
// ===========================================================================
__global__ __launch_bounds__(256)
void fused_kernel(const int* __restrict__ node_ids, const int* __restrict__ edge_ids,
                  const int* __restrict__ src, const int* __restrict__ dst,
                  const float* __restrict__ node_table, const float* __restrict__ edge_table,
                  const float* __restrict__ proj_W, const float* __restrict__ proj_b,
                  const float* __restrict__ attn_w,
                  const float* __restrict__ e1_W1, const float* __restrict__ e1_b1,
                  const float* __restrict__ e1_W2, const float* __restrict__ e1_b2,
                  const float* __restrict__ e2_W1, const float* __restrict__ e2_b1,
                  const float* __restrict__ e2_W2, const float* __restrict__ e2_b2,
                  const float* __restrict__ gWih, const float* __restrict__ gWhh,
                  const float* __restrict__ gbih, const float* __restrict__ gbhh,
                  float* __restrict__ Wt, float* __restrict__ h0, float* __restrict__ h1,
                  int* __restrict__ rs, int* __restrict__ edge_p, int* __restrict__ bar,
                  float4* __restrict__ Wpk4, float2* __restrict__ Wpk2,
                  float* __restrict__ out, int nblk)
{
    const int T  = nblk * 256;
    const int t0 = blockIdx.x * 256 + threadIdx.x;
    const int subsz = nblk >> 5;                    // nblk multiple of 32

    // ---------------- Phase 0 (incl. degree count) ------------------------
    for (int t = t0; t < PH0_TOTAL; t += T) {
        if (t < TASK_VOCAB) {
            int v = t >> 10, f = t & 1023, l = t & 63;   // v wave-uniform
            const float* W1 = (v < N_BOND) ? e1_W1 : e2_W1;
            const float* b1 = (v < N_BOND) ? e1_b1 : e2_b1;
            const float* W2 = (v < N_BOND) ? e1_W2 : e2_W2;
            const float* b2 = (v < N_BOND) ? e1_b2 : e2_b2;
            const float4* ef4 = (const float4*)(edge_table + v * EDGE_INDIM);
            const float4* w14 = (const float4*)(W1 + l * EDGE_INDIM);
            float z = b1[l];
            #pragma unroll
            for (int j = 0; j < 8; ++j) {
                float4 a = ef4[j], b = w14[j];
                z += a.x*b.x + a.y*b.y + a.z*b.z + a.w*b.w;
            }
            z = fmaxf(z, 0.f);
            float y = b2[f];
            const float4* w24 = (const float4*)(W2 + f * EH);
            #pragma unroll
            for (int k = 0; k < 16; ++k) {
                float4 w = w24[k];
                y += __shfl(z, 4*k,   64) * w.x + __shfl(z, 4*k+1, 64) * w.y
                   + __shfl(z, 4*k+2, 64) * w.z + __shfl(z, 4*k+3, 64) * w.w;
            }
            Wt[(v << 10) + f] = y;                       // [v][i*32+o]
        } else if (t < TASK_VOCAB + TASK_PROJ) {
            int q = t - TASK_VOCAB;
            int n = q >> 5, o = q & 31;
            int gid = node_ids[n];
            const float4* nf4 = (const float4*)(node_table + (size_t)gid * NODE_INDIM);
            const float4* wr4 = (const float4*)(proj_W + o * NODE_INDIM);
            float acc = proj_b[o];
            #pragma unroll
            for (int j = 0; j < 16; ++j) {
                float4 a = nf4[j], b = wr4[j];
                acc += a.x*b.x + a.y*b.y + a.z*b.z + a.w*b.w;
            }
            h0[q] = fmaxf(acc, 0.f);
        } else if (t < TASK_DEG_BASE) {
            int q = t - (TASK_VOCAB + TASK_PROJ);        // q = j*32 + o
            int j = q >> 5, o = q & 31;
            Wpk4[q] = make_float4(gWih[o * 32 + j], gWih[(32 + o) * 32 + j],
                                  gWih[(64 + o) * 32 + j], gWhh[o * 32 + j]);
            Wpk2[q] = make_float2(gWhh[(32 + o) * 32 + j], gWhh[(64 + o) * 32 + j]);
        } else {
            atomicAdd(&rs[dst[t - TASK_DEG_BASE]], 1);   // rs pre-zeroed (memset)
        }
    }
    gbar(bar, 1, subsz);

    // ---------------- Phase 1: exclusive scan (block 0) -------------------
    if (blockIdx.x == 0) {
        __shared__ int s_sum[256];
        __shared__ int s_wsum[4];
        const int CH = (N_NODES + 255) / 256;            // 59
        int base = threadIdx.x * CH;
        int sum = 0;
        for (int k = 0; k < CH; ++k) { int i = base + k; if (i < N_NODES) sum += rs[i]; }
        s_sum[threadIdx.x] = sum;
        __syncthreads();
        int lane = threadIdx.x & 63, wv = threadIdx.x >> 6;
        int v = s_sum[threadIdx.x];
        #pragma unroll
        for (int off = 1; off < 64; off <<= 1) {
            int u = __shfl_up(v, off, 64);
            if (lane >= off) v += u;
        }
        if (lane == 63) s_wsum[wv] = v;
        __syncthreads();
        int wbase = 0;
        for (int w = 0; w < wv; ++w) wbase += s_wsum[w];
        int run = wbase + (v - sum);                     // exclusive thread prefix
        for (int k = 0; k < CH; ++k) {
            int i = base + k;
            if (i < N_NODES) { int d = rs[i]; rs[i] = run; run += d; }
        }
    }
    gbar(bar, 2, subsz);

    // ---------------- Phase 2: scatter sorted-by-dst ----------------------
    for (int e = t0; e < N_EDGES; e += T) {
        int pos = atomicAdd(&rs[dst[e]], 1);
        edge_p[pos] = src[e] | (edge_ids[e] << 16);      // src<2^14, vocab<54
    }
    gbar(bar, 3, subsz);
    // post-scatter: rs[n] = end(n);  start(n) = n ? rs[n-1] : 0

    // ---------------- 3 MP steps (gather + softmax + GRU fused) -----------
    float* hc = h0;
    float* hn = h1;
    for (int step = 0; step < 3; ++step) {
        float* op = (step == 2) ? out : hn;
        for (int t = t0; t < N_NODES * H; t += T) {
            int n = t >> 5, o = t & 31;
            int pbeg = (n == 0) ? 0 : rs[n - 1];
            int pend = rs[n];
            float hv = hc[t];
            float w1 = attn_w[o], w2 = attn_w[32 + o];
            float bd = hv * w2;                          // dst half of logit
            #pragma unroll
            for (int k = 16; k > 0; k >>= 1) bd += __shfl_xor(bd, k, 32);
            float sex = 0.f, acc = 0.f;
            for (int p = pbeg; p < pend; ++p) {
                int pk = edge_p[p];
                int sp = pk & 0xFFFF, vp = pk >> 16;
                float hs = hc[(sp << 5) + o];
                float as = hs * w1;
                #pragma unroll
                for (int k = 16; k > 0; k >>= 1) as += __shfl_xor(as, k, 32);
                float a = as + bd;
                a = (a > 0.f) ? a : 0.01f * a;           // leaky_relu
                float ex = __expf(a);
                sex += ex;
                const float* W = Wt + (vp << 10) + o;    // column o, coalesced
                float y = 0.f;
                #pragma unroll
                for (int i = 0; i < 32; ++i) y += __shfl(hs, i, 32) * W[i * 32];
                acc += ex * y;
            }
            float m = (pend > pbeg) ? fmaxf(acc / sex, 0.f) : 0.f;
            float gir = 0.f, giz = 0.f, gin = 0.f, ghr = 0.f, ghz = 0.f, ghn = 0.f;
            #pragma unroll 4
            for (int j = 0; j < 32; ++j) {
                float mj = __shfl(m, j, 32);
                float hj = __shfl(hv, j, 32);
                float4 a4 = Wpk4[j * 32 + o];
                float2 b2 = Wpk2[j * 32 + o];
                gir += mj * a4.x;  giz += mj * a4.y;  gin += mj * a4.z;
                ghr += hj * a4.w;  ghz += hj * b2.x;  ghn += hj * b2.y;
            }
            float r  = 1.f / (1.f + __expf(-(gir + gbih[o]      + ghr + gbhh[o])));
            float z  = 1.f / (1.f + __expf(-(giz + gbih[32 + o] + ghz + gbhh[32 + o])));
            float nn = tanhf(gin + gbih[64 + o] + r * (ghn + gbhh[64 + o]));
            op[t] = (1.f - z) * nn + z * hv;
        }
        if (step < 2) gbar(bar, 4 + step, subsz);
        float* tmp = hc; hc = hn; hn = tmp;
    }
}

// ===========================================================================
// Fallback: known-good 7-launch pipeline (226 us) if coop launch unavailable.
// ===========================================================================
#define FB_TASK_ZERO ((N_NODES * H + N_NODES) / 4)
#define FB_TA (TASK_VOCAB + TASK_PROJ + FB_TASK_ZERO + TASK_PACK)

__global__ void setup_kernel(const int* __restrict__ node_ids,
                             const float* __restrict__ node_table,
                             const float* __restrict__ edge_table,
                             const float* __restrict__ proj_W, const float* __restrict__ proj_b,
                             const float* __restrict__ e1_W1, const float* __restrict__ e1_b1,
                             const float* __restrict__ e1_W2, const float* __restrict__ e1_b2,
                             const float* __restrict__ e2_W1, const float* __restrict__ e2_b1,
                             const float* __restrict__ e2_W2, const float* __restrict__ e2_b2,
                             const float* __restrict__ gWih, const float* __restrict__ gWhh,
                             float* __restrict__ Wt, float* __restrict__ h,
                             float* __restrict__ agg,
                             float4* __restrict__ Wpk4, float2* __restrict__ Wpk2) {
    int t = blockIdx.x * 256 + threadIdx.x;
    if (t >= FB_TA) return;
    if (t < TASK_VOCAB) {
        int v = t >> 10, f = t & 1023, l = t & 63;
        const float* W1 = (v < N_BOND) ? e1_W1 : e2_W1;
        const float* b1 = (v < N_BOND) ? e1_b1 : e2_b1;
        const float* W2 = (v < N_BOND) ? e1_W2 : e2_W2;
        const float* b2 = (v < N_BOND) ? e1_b2 : e2_b2;
        const float* ef = edge_table + v * EDGE_INDIM;
        float z = b1[l];
        const float* w1r = W1 + l * EDGE_INDIM;
        #pragma unroll
        for (int j = 0; j < EDGE_INDIM; ++j) z += ef[j] * w1r[j];
        z = fmaxf(z, 0.f);
        float y = b2[f];
        const float* w2r = W2 + f * EH;
        #pragma unroll
        for (int k = 0; k < EH; ++k) y += __shfl(z, k, 64) * w2r[k];
        Wt[v * 1024 + f] = y;
    } else if (t < TASK_VOCAB + TASK_PROJ) {
        int q = t - TASK_VOCAB;
        int n = q >> 5, o = q & 31;
        int gid = node_ids[n];
        const float* nf = node_table + (size_t)gid * NODE_INDIM;
        const float* wr = proj_W + o * NODE_INDIM;
        float acc = proj_b[o];
        #pragma unroll 8
        for (int j = 0; j < NODE_INDIM; ++j) acc += nf[j] * wr[j];
        h[q] = fmaxf(acc, 0.f);
    } else if (t < TASK_VOCAB + TASK_PROJ + FB_TASK_ZERO) {
        int q = t - TASK_VOCAB - TASK_PROJ;
        ((float4*)agg)[q] = make_float4(0.f, 0.f, 0.f, 0.f);
    } else {
        int q = t - TASK_VOCAB - TASK_PROJ - FB_TASK_ZERO;
        int j = q >> 5, o = q & 31;
        Wpk4[q] = make_float4(gWih[o * 32 + j], gWih[(32 + o) * 32 + j],
                              gWih[(64 + o) * 32 + j], gWhh[o * 32 + j]);
        Wpk2[q] = make_float2(gWhh[(32 + o) * 32 + j], gWhh[(64 + o) * 32 + j]);
    }
}

__launch_bounds__(256)
__global__ void edge_kernel(const int* __restrict__ src, const int* __restrict__ dst,
                            const int* __restrict__ edge_ids,
                            const float* __restrict__ h, const float* __restrict__ Wt,
                            const float* __restrict__ attn_w,
                            float* __restrict__ agg, float* __restrict__ sm) {
    int t = blockIdx.x * 256 + threadIdx.x;
    int e = t >> 5, o = t & 31;
    int s = src[e], d = dst[e], v = edge_ids[e];
    float hs = h[s * 32 + o];
    float val = hs * attn_w[o] + h[d * 32 + o] * attn_w[32 + o];
    #pragma unroll
    for (int k = 16; k > 0; k >>= 1) val += __shfl_xor(val, k, 32);
    float a  = (val > 0.f) ? val : 0.01f * val;
    float ex = __expf(a);
    const float* W = Wt + v * 1024 + o;
    float y = 0.f;
    #pragma unroll
    for (int i = 0; i < 32; ++i)
        y += __shfl(hs, i, 32) * W[i * 32];
    atomicAdd(&agg[d * 32 + o], ex * y);
    if (o == 0) atomicAdd(&sm[d], ex);
}

__launch_bounds__(256)
__global__ void gru_kernel(float* __restrict__ agg, float* __restrict__ sm,
                           const float* __restrict__ h,
                           const float4* __restrict__ Wpk4, const float2* __restrict__ Wpk2,
                           const float* __restrict__ gbih, const float* __restrict__ gbhh,
                           float* __restrict__ hout) {
    int t = blockIdx.x * 256 + threadIdx.x;
    int n = t >> 5, o = t & 31;
    float sinv = 1.f / sm[n];
    float m  = fmaxf(agg[t] * sinv, 0.f);
    float hv = h[t];
    float gir = 0.f, giz = 0.f, gin = 0.f, ghr = 0.f, ghz = 0.f, ghn = 0.f;
    #pragma unroll 8
    for (int j = 0; j < 32; ++j) {
        float mj = __shfl(m, j, 32);
        float hj = __shfl(hv, j, 32);
        float4 a = Wpk4[j * 32 + o];
        float2 b = Wpk2[j * 32 + o];
        gir += mj * a.x;  giz += mj * a.y;  gin += mj * a.z;
        ghr += hj * a.w;  ghz += hj * b.x;  ghn += hj * b.y;
    }
    float r  = 1.f / (1.f + __expf(-(gir + gbih[o]      + ghr + gbhh[o])));
    float z  = 1.f / (1.f + __expf(-(giz + gbih[32 + o] + ghz + gbhh[32 + o])));
    float nn = tanhf(gin + gbih[64 + o] + r * (ghn + gbhh[64 + o]));
    hout[t] = (1.f - z) * nn + z * hv;
    agg[t] = 0.f;
    if (o == 0) sm[n] = 0.f;
}

// ===========================================================================
extern "C" void kernel_launch(void* const* d_in, const int* in_sizes, int n_in,
                              void* d_out, int out_size, void* d_ws, size_t ws_size,
                              hipStream_t stream) {
    const int*   node_ids   = (const int*)d_in[0];
    const int*   edge_ids   = (const int*)d_in[1];
    const int*   srcp       = (const int*)d_in[2];
    const int*   dstp       = (const int*)d_in[3];
    const float* node_table = (const float*)d_in[4];
    const float* edge_table = (const float*)d_in[5];
    const float* proj_W     = (const float*)d_in[6];
    const float* proj_b     = (const float*)d_in[7];
    const float* attn_w     = (const float*)d_in[8];
    const float* e1_W1 = (const float*)d_in[9];  const float* e1_b1 = (const float*)d_in[10];
    const float* e1_W2 = (const float*)d_in[11]; const float* e1_b2 = (const float*)d_in[12];
    const float* e2_W1 = (const float*)d_in[13]; const float* e2_b1 = (const float*)d_in[14];
    const float* e2_W2 = (const float*)d_in[15]; const float* e2_b2 = (const float*)d_in[16];
    const float* gWih  = (const float*)d_in[17]; const float* gWhh  = (const float*)d_in[18];
    const float* gbih  = (const float*)d_in[19]; const float* gbhh  = (const float*)d_in[20];
    float* outp = (float*)d_out;

    char* ws = (char*)d_ws;
    float*  Wt   = (float*)(ws + WT_OFF);
    float*  h0b  = (float*)(ws + H0_OFF);
    float*  h1b  = (float*)(ws + H1_OFF);
    int*    epk  = (int*)  (ws + EPK_OFF);
    float4* Wpk4 = (float4*)(ws + W4_OFF);
    float2* Wpk2 = (float2*)(ws + W2_OFF);
    int*    rs   = (int*)  (ws + RS_OFF);
    int*    bar  = (int*)  (ws + BAR_OFF);

    // cooperative grid: multiple of 32 blocks, <=1024, guaranteed co-resident
    static int coop_grid = -2;
    if (coop_grid == -2) {
        int nb = 0;
        hipError_t qe = hipOccupancyMaxActiveBlocksPerMultiprocessor(&nb, fused_kernel, 256, 0);
        if (qe == hipSuccess && nb > 0) {
            long g = (long)nb * 256;
            if (g > 1024) g = 1024;
            g = (g / 32) * 32;
            coop_grid = (g >= 32) ? (int)g : -1;
        } else {
            coop_grid = -1;
        }
        (void)hipGetLastError();
    }

    hipError_t lerr = hipErrorUnknown;
    if (coop_grid > 0) {
        // zero rs (degree counters) + barrier state in one memset
        hipError_t me = hipMemsetAsync(ws + RS_OFF, 0, 60000 + 4096, stream);
        if (me == hipSuccess) {
            int nblk = coop_grid;
            void* args[] = {
                (void*)&node_ids, (void*)&edge_ids, (void*)&srcp, (void*)&dstp,
                (void*)&node_table, (void*)&edge_table, (void*)&proj_W, (void*)&proj_b,
                (void*)&attn_w,
                (void*)&e1_W1, (void*)&e1_b1, (void*)&e1_W2, (void*)&e1_b2,
                (void*)&e2_W1, (void*)&e2_b1, (void*)&e2_W2, (void*)&e2_b2,
                (void*)&gWih, (void*)&gWhh, (void*)&gbih, (void*)&gbhh,
                (void*)&Wt, (void*)&h0b, (void*)&h1b, (void*)&rs, (void*)&epk,
                (void*)&bar, (void*)&Wpk4, (void*)&Wpk2, (void*)&outp, (void*)&nblk
            };
            lerr = hipLaunchCooperativeKernel(fused_kernel, dim3(coop_grid), dim3(256),
                                              args, 0, stream);
            if (lerr != hipSuccess) { (void)hipGetLastError(); coop_grid = -1; }
        } else {
            (void)hipGetLastError();
            coop_grid = -1;
        }
    }

    if (lerr != hipSuccess) {
        // -------- fallback: previous 7-launch pipeline --------
        float*  h    = (float*)(ws + 221184);
        float*  agg  = (float*)(ws + 2141184);
        float*  sm   = (float*)(ws + 4061184);
        float4* fW4  = (float4*)(ws + 4121184);
        float2* fW2  = (float2*)(ws + 4137568);
        setup_kernel<<<(FB_TA + 255) / 256, 256, 0, stream>>>(
            node_ids, node_table, edge_table, proj_W, proj_b,
            e1_W1, e1_b1, e1_W2, e1_b2, e2_W1, e2_b1, e2_W2, e2_b2,
            gWih, gWhh, Wt, h, agg, fW4, fW2);
        for (int step = 0; step < 3; ++step) {
            edge_kernel<<<(N_EDGES * 32) / 256, 256, 0, stream>>>(
                srcp, dstp, edge_ids, h, Wt, attn_w, agg, sm);
            float* hout = (step == 2) ? outp : h;
            gru_kernel<<<(N_NODES * 32) / 256, 256, 0, stream>>>(
                agg, sm, h, fW4, fW2, gbih, gbhh, hout);
        }
    }
}

// Round 3
// 294.389 us; speedup vs baseline: 2.6305x; 2.6305x over previous
//
#include <hip/hip_runtime.h>
#include <math.h>

#define N_NODES   15000
#define N_EDGES   60000
#define EVOCAB    54
#define NODE_INDIM 64
#define EDGE_INDIM 32
#define H  32
#define EH 64
#define N_BOND 4

// ---- setup task layout (segment bases 64-aligned so 32-lane shfl groups never straddle) ----
#define TASK_VOCAB (EVOCAB * 1024)                 // 55296
#define TASK_PROJ  (N_NODES * H)                   // 480000
#define TASK_PACK  (H * H)                         // 1024
#define TASK_DEG_BASE (TASK_VOCAB + TASK_PROJ + TASK_PACK)   // 536320
#define TA_TOTAL   (TASK_DEG_BASE + N_EDGES)                 // 596320

// ---- workspace offsets (bytes); harness ws is ~268 MB, we use ~4.6 MB ----
#define WT_OFF  0          // 221184 B  vocab weight table [54][1024]
#define H0_OFF  221184     // 1920000 B
#define H1_OFF  2141184    // 1920000 B
#define EPK_OFF 4061184    // 240000 B  packed CSR edges
#define W4_OFF  4301184    // 16384 B   GRU packed float4
#define W2_OFF  4317568    // 8192 B    GRU packed float2
#define RS_OFF  4325760    // 60000 B   degree -> prefix -> end offsets
#define LS0_OFF 4385760    // 60000 B   per-node src-logit  (pairs with h0)
#define BS0_OFF 4445760    // 60000 B   per-node dst-logit  (pairs with h0)
#define LS1_OFF 4505760    // 60000 B   (pairs with h1)
#define BS1_OFF 4565760    // 60000 B

// ===========================================================================
// K1 setup: vocab Wt | h0 projection (+ ls0/bs0 attention scalars) | GRU pack
//           | in-degree count (rs pre-zeroed by hipMemsetAsync)
// ===========================================================================
__global__ __launch_bounds__(256)
void setup_kernel(const int* __restrict__ node_ids, const int* __restrict__ dst,
                  const float* __restrict__ node_table, const float* __restrict__ edge_table,
                  const float* __restrict__ proj_W, const float* __restrict__ proj_b,
                  const float* __restrict__ attn_w,
                  const float* __restrict__ e1_W1, const float* __restrict__ e1_b1,
                  const float* __restrict__ e1_W2, const float* __restrict__ e1_b2,
                  const float* __restrict__ e2_W1, const float* __restrict__ e2_b1,
                  const float* __restrict__ e2_W2, const float* __restrict__ e2_b2,
                  const float* __restrict__ gWih, const float* __restrict__ gWhh,
                  float* __restrict__ Wt, float* __restrict__ h0,
                  float* __restrict__ ls, float* __restrict__ bs,
                  float4* __restrict__ Wpk4, float2* __restrict__ Wpk2,
                  int* __restrict__ rs)
{
    int t = blockIdx.x * 256 + threadIdx.x;
    if (t >= TA_TOTAL) return;
    if (t < TASK_VOCAB) {
        int v = t >> 10, f = t & 1023, l = t & 63;       // v wave-uniform
        const float* W1 = (v < N_BOND) ? e1_W1 : e2_W1;
        const float* b1 = (v < N_BOND) ? e1_b1 : e2_b1;
        const float* W2 = (v < N_BOND) ? e1_W2 : e2_W2;
        const float* b2 = (v < N_BOND) ? e1_b2 : e2_b2;
        const float4* ef4 = (const float4*)(edge_table + v * EDGE_INDIM);
        const float4* w14 = (const float4*)(W1 + l * EDGE_INDIM);
        float z = b1[l];
        #pragma unroll
        for (int j = 0; j < 8; ++j) {
            float4 a = ef4[j], b = w14[j];
            z += a.x*b.x + a.y*b.y + a.z*b.z + a.w*b.w;
        }
        z = fmaxf(z, 0.f);
        float y = b2[f];
        const float4* w24 = (const float4*)(W2 + f * EH);
        #pragma unroll
        for (int k = 0; k < 16; ++k) {
            float4 w = w24[k];
            y += __shfl(z, 4*k,   64) * w.x + __shfl(z, 4*k+1, 64) * w.y
               + __shfl(z, 4*k+2, 64) * w.z + __shfl(z, 4*k+3, 64) * w.w;
        }
        Wt[(v << 10) + f] = y;                           // [v][i*32+o]
    } else if (t < TASK_VOCAB + TASK_PROJ) {
        int q = t - TASK_VOCAB;
        int n = q >> 5, o = q & 31;
        int gid = node_ids[n];
        const float4* nf4 = (const float4*)(node_table + (size_t)gid * NODE_INDIM);
        const float4* wr4 = (const float4*)(proj_W + o * NODE_INDIM);
        float acc = proj_b[o];
        #pragma unroll
        for (int j = 0; j < 16; ++j) {
            float4 a = nf4[j], b = wr4[j];
            acc += a.x*b.x + a.y*b.y + a.z*b.z + a.w*b.w;
        }
        float hval = fmaxf(acc, 0.f);
        h0[q] = hval;
        // per-node attention scalars: ls = h.w1, bs = h.w2 (kills per-edge reduces)
        float c1 = hval * attn_w[o], c2 = hval * attn_w[32 + o];
        #pragma unroll
        for (int k = 16; k > 0; k >>= 1) {
            c1 += __shfl_xor(c1, k, 32);
            c2 += __shfl_xor(c2, k, 32);
        }
        if (o == 0) { ls[n] = c1; bs[n] = c2; }
    } else if (t < TASK_DEG_BASE) {
        int q = t - (TASK_VOCAB + TASK_PROJ);            // q = j*32 + o
        int j = q >> 5, o = q & 31;
        Wpk4[q] = make_float4(gWih[o * 32 + j], gWih[(32 + o) * 32 + j],
                              gWih[(64 + o) * 32 + j], gWhh[o * 32 + j]);
        Wpk2[q] = make_float2(gWhh[(32 + o) * 32 + j], gWhh[(64 + o) * 32 + j]);
    } else {
        atomicAdd(&rs[dst[t - TASK_DEG_BASE]], 1);       // rs pre-zeroed
    }
}

// ===========================================================================
// K2 scan: exclusive prefix over 15000 degrees, single block.
// ===========================================================================
__global__ __launch_bounds__(256)
void scan_kernel(int* __restrict__ rs)
{
    __shared__ int s_sum[256];
    __shared__ int s_wsum[4];
    const int CH = (N_NODES + 255) / 256;                // 59
    int base = threadIdx.x * CH;
    int sum = 0;
    for (int k = 0; k < CH; ++k) { int i = base + k; if (i < N_NODES) sum += rs[i]; }
    s_sum[threadIdx.x] = sum;
    __syncthreads();
    int lane = threadIdx.x & 63, wv = threadIdx.x >> 6;
    int v = s_sum[threadIdx.x];
    #pragma unroll
    for (int off = 1; off < 64; off <<= 1) {
        int u = __shfl_up(v, off, 64);
        if (lane >= off) v += u;
    }
    if (lane == 63) s_wsum[wv] = v;
    __syncthreads();
    int wbase = 0;
    for (int w = 0; w < wv; ++w) wbase += s_wsum[w];
    int run = wbase + (v - sum);                         // exclusive thread prefix
    for (int k = 0; k < CH; ++k) {
        int i = base + k;
        if (i < N_NODES) { int d = rs[i]; rs[i] = run; run += d; }
    }
}

// ===========================================================================
// K3 scatter: CSR edge list sorted by dst.  edge_p[pos] = src | (vocab<<16)
// After this, rs[n] = end(n); start(n) = n ? rs[n-1] : 0.
// ===========================================================================
__global__ __launch_bounds__(256)
void scatter_kernel(const int* __restrict__ src, const int* __restrict__ dst,
                    const int* __restrict__ eid,
                    int* __restrict__ rs, int* __restrict__ edge_p)
{
    int e = blockIdx.x * 256 + threadIdx.x;
    if (e >= N_EDGES) return;
    int pos = atomicAdd(&rs[dst[e]], 1);
    edge_p[pos] = src[e] | (eid[e] << 16);               // src<2^14, vocab<54
}

// ===========================================================================
// K4-6 mp: one kernel per message-passing step. Per-dst CSR gather (scalar
// logit via ls/bs tables, 32x32 matvec w/ 4-way split accumulators) fused
// with softmax-normalize + relu + GRU. Writes next step's ls/bs.
// No float atomics anywhere.
// ===========================================================================
__global__ __launch_bounds__(256)
void mp_kernel(const int* __restrict__ rs, const int* __restrict__ edge_p,
               const float* __restrict__ hc, const float* __restrict__ Wt,
               const float* __restrict__ attn_w,
               const float4* __restrict__ Wpk4, const float2* __restrict__ Wpk2,
               const float* __restrict__ gbih, const float* __restrict__ gbhh,
               const float* __restrict__ lsc, const float* __restrict__ bsc,
               float* __restrict__ lsn, float* __restrict__ bsn,
               float* __restrict__ op, int last)
{
    int t = blockIdx.x * 256 + threadIdx.x;              // t < 480000 exact grid
    int n = t >> 5, o = t & 31;
    int pbeg = (n == 0) ? 0 : rs[n - 1];
    int pend = rs[n];
    float hv = hc[t];
    float bdn = bsc[n];                                  // dst half of logit (scalar)
    float sex = 0.f, acc = 0.f;
    for (int p = pbeg; p < pend; ++p) {
        int pk = edge_p[p];                              // wave-uniform broadcast
        int sp = pk & 0xFFFF, vp = pk >> 16;
        float a = lsc[sp] + bdn;                         // logit: 1 scalar load
        a = (a > 0.f) ? a : 0.01f * a;                   // leaky_relu
        float ex = __expf(a);
        sex += ex;
        float hs = hc[(sp << 5) + o];
        const float* W = Wt + (vp << 10) + o;            // column o, coalesced rows
        float y0 = 0.f, y1 = 0.f, y2 = 0.f, y3 = 0.f;    // 4-way chain split
        #pragma unroll
        for (int i = 0; i < 8; ++i) {
            y0 += __shfl(hs, 4*i,     32) * W[(4*i    ) * 32];
            y1 += __shfl(hs, 4*i + 1, 32) * W[(4*i + 1) * 32];
            y2 += __shfl(hs, 4*i + 2, 32) * W[(4*i + 2) * 32];
            y3 += __shfl(hs, 4*i + 3, 32) * W[(4*i + 3) * 32];
        }
        acc += ex * ((y0 + y1) + (y2 + y3));
    }
    float m = (pend > pbeg) ? fmaxf(acc / sex, 0.f) : 0.f;
    // GRU cell, packed-transposed weights (coalesced 512B broadcast reads)
    float gir = 0.f, giz = 0.f, gin = 0.f, ghr = 0.f, ghz = 0.f, ghn = 0.f;
    #pragma unroll 4
    for (int j = 0; j < 32; ++j) {
        float mj = __shfl(m, j, 32);
        float hj = __shfl(hv, j, 32);
        float4 a4 = Wpk4[j * 32 + o];
        float2 b2 = Wpk2[j * 32 + o];
        gir += mj * a4.x;  giz += mj * a4.y;  gin += mj * a4.z;
        ghr += hj * a4.w;  ghz += hj * b2.x;  ghn += hj * b2.y;
    }
    float r  = 1.f / (1.f + __expf(-(gir + gbih[o]      + ghr + gbhh[o])));
    float z  = 1.f / (1.f + __expf(-(giz + gbih[32 + o] + ghz + gbhh[32 + o])));
    float nn = tanhf(gin + gbih[64 + o] + r * (ghn + gbhh[64 + o]));
    float hid = (1.f - z) * nn + z * hv;
    op[t] = hid;
    if (!last) {                                         // next step's attention scalars
        float c1 = hid * attn_w[o], c2 = hid * attn_w[32 + o];
        #pragma unroll
        for (int k = 16; k > 0; k >>= 1) {
            c1 += __shfl_xor(c1, k, 32);
            c2 += __shfl_xor(c2, k, 32);
        }
        if (o == 0) { lsn[n] = c1; bsn[n] = c2; }
    }
}

// ===========================================================================
extern "C" void kernel_launch(void* const* d_in, const int* in_sizes, int n_in,
                              void* d_out, int out_size, void* d_ws, size_t ws_size,
                              hipStream_t stream) {
    const int*   node_ids   = (const int*)d_in[0];
    const int*   edge_ids   = (const int*)d_in[1];
    const int*   srcp       = (const int*)d_in[2];
    const int*   dstp       = (const int*)d_in[3];
    const float* node_table = (const float*)d_in[4];
    const float* edge_table = (const float*)d_in[5];
    const float* proj_W     = (const float*)d_in[6];
    const float* proj_b     = (const float*)d_in[7];
    const float* attn_w     = (const float*)d_in[8];
    const float* e1_W1 = (const float*)d_in[9];  const float* e1_b1 = (const float*)d_in[10];
    const float* e1_W2 = (const float*)d_in[11]; const float* e1_b2 = (const float*)d_in[12];
    const float* e2_W1 = (const float*)d_in[13]; const float* e2_b1 = (const float*)d_in[14];
    const float* e2_W2 = (const float*)d_in[15]; const float* e2_b2 = (const float*)d_in[16];
    const float* gWih  = (const float*)d_in[17]; const float* gWhh  = (const float*)d_in[18];
    const float* gbih  = (const float*)d_in[19]; const float* gbhh  = (const float*)d_in[20];
    float* outp = (float*)d_out;

    char* ws = (char*)d_ws;
    float*  Wt   = (float*)(ws + WT_OFF);
    float*  h0b  = (float*)(ws + H0_OFF);
    float*  h1b  = (float*)(ws + H1_OFF);
    int*    epk  = (int*)  (ws + EPK_OFF);
    float4* Wpk4 = (float4*)(ws + W4_OFF);
    float2* Wpk2 = (float2*)(ws + W2_OFF);
    int*    rs   = (int*)  (ws + RS_OFF);
    float*  ls0  = (float*)(ws + LS0_OFF);
    float*  bs0  = (float*)(ws + BS0_OFF);
    float*  ls1  = (float*)(ws + LS1_OFF);
    float*  bs1  = (float*)(ws + BS1_OFF);

    // zero degree counters (graph-capture-safe async fill)
    hipMemsetAsync(ws + RS_OFF, 0, 60000, stream);

    setup_kernel<<<(TA_TOTAL + 255) / 256, 256, 0, stream>>>(
        node_ids, dstp, node_table, edge_table, proj_W, proj_b, attn_w,
        e1_W1, e1_b1, e1_W2, e1_b2, e2_W1, e2_b1, e2_W2, e2_b2,
        gWih, gWhh, Wt, h0b, ls0, bs0, Wpk4, Wpk2, rs);

    scan_kernel<<<1, 256, 0, stream>>>(rs);

    scatter_kernel<<<(N_EDGES + 255) / 256, 256, 0, stream>>>(
        srcp, dstp, edge_ids, rs, epk);

    float* hc = h0b;  float* hn = h1b;
    float* lc = ls0;  float* bc = bs0;
    float* ln = ls1;  float* bn = bs1;
    for (int step = 0; step < 3; ++step) {
        int last = (step == 2);
        float* op = last ? outp : hn;
        mp_kernel<<<(N_NODES * H) / 256, 256, 0, stream>>>(
            rs, epk, hc, Wt, attn_w, Wpk4, Wpk2, gbih, gbhh,
            lc, bc, ln, bn, op, last);
        float* tf;
        tf = hc; hc = hn; hn = tf;
        tf = lc; lc = ln; ln = tf;
        tf = bc; bc = bn; bn = tf;
    }
}

// Round 4
// 220.479 us; speedup vs baseline: 3.5123x; 1.3352x over previous
//
#include <hip/hip_runtime.h>
#include <math.h>

#define N_NODES   15000
#define N_EDGES   60000
#define EVOCAB    54
#define NODE_INDIM 64
#define EDGE_INDIM 32
#define H  32
#define EH 64
#define N_BOND 4

#define NPB   8          // nodes per block (15000/8 = 1875 blocks exact)
#define NBLK  (N_NODES / NPB)            // 1875
#define CAP   128        // per-block edge capacity (avg 32, P[Poisson(32)>128]~1e-40)

// ---- setup task layout (segment bases 64-aligned so shfl groups never straddle) ----
#define TASK_VOCAB (EVOCAB * 1024)                 // 55296
#define TASK_PROJ  (N_NODES * H)                   // 480000
#define TASK_PACK  (H * H)                         // 1024
#define TASK_EDGE_BASE (TASK_VOCAB + TASK_PROJ + TASK_PACK)  // 536320
#define TA_TOTAL   (TASK_EDGE_BASE + N_EDGES)                // 596320

// ---- workspace offsets (bytes) ----
#define WT_OFF  0          // 221184  vocab weight table [54][1024]
#define H0_OFF  221184     // 1920000
#define H1_OFF  2141184    // 1920000
#define W4_OFF  4061184    // 16384   GRU packed float4
#define W2_OFF  4077568    // 8192    GRU packed float2
#define LS0_OFF 4085760    // 60000   per-node src-logit (pairs h0)
#define BS0_OFF 4145760    // 60000   per-node dst-logit (pairs h0)
#define LS1_OFF 4205760    // 60000
#define BS1_OFF 4265760    // 60000
#define CNT_OFF 4325760    // 7680    per-block edge counters (memset 0)
#define EPK_OFF 4333440    // 960000  bucketed packed edges [1875][128]

// ===========================================================================
// K1 setup: vocab Wt | h0 projection (+ls0/bs0) | GRU pack | edge bucketing.
// Edge pack: src(14b) | vid(6b)<<14 | dstlocal(3b)<<20, bucket = dst>>3.
// ===========================================================================
__global__ __launch_bounds__(256)
void setup_kernel(const int* __restrict__ node_ids, const int* __restrict__ src,
                  const int* __restrict__ dst, const int* __restrict__ eid,
                  const float* __restrict__ node_table, const float* __restrict__ edge_table,
                  const float* __restrict__ proj_W, const float* __restrict__ proj_b,
                  const float* __restrict__ attn_w,
                  const float* __restrict__ e1_W1, const float* __restrict__ e1_b1,
                  const float* __restrict__ e1_W2, const float* __restrict__ e1_b2,
                  const float* __restrict__ e2_W1, const float* __restrict__ e2_b1,
                  const float* __restrict__ e2_W2, const float* __restrict__ e2_b2,
                  const float* __restrict__ gWih, const float* __restrict__ gWhh,
                  float* __restrict__ Wt, float* __restrict__ h0,
                  float* __restrict__ ls, float* __restrict__ bs,
                  float4* __restrict__ Wpk4, float2* __restrict__ Wpk2,
                  int* __restrict__ cnt, int* __restrict__ blkE)
{
    int t = blockIdx.x * 256 + threadIdx.x;
    if (t >= TA_TOTAL) return;
    if (t < TASK_VOCAB) {
        int v = t >> 10, f = t & 1023, l = t & 63;       // v wave-uniform
        const float* W1 = (v < N_BOND) ? e1_W1 : e2_W1;
        const float* b1 = (v < N_BOND) ? e1_b1 : e2_b1;
        const float* W2 = (v < N_BOND) ? e1_W2 : e2_W2;
        const float* b2 = (v < N_BOND) ? e1_b2 : e2_b2;
        const float4* ef4 = (const float4*)(edge_table + v * EDGE_INDIM);
        const float4* w14 = (const float4*)(W1 + l * EDGE_INDIM);
        float z = b1[l];
        #pragma unroll
        for (int j = 0; j < 8; ++j) {
            float4 a = ef4[j], b = w14[j];
            z += a.x*b.x + a.y*b.y + a.z*b.z + a.w*b.w;
        }
        z = fmaxf(z, 0.f);
        float y = b2[f];
        const float4* w24 = (const float4*)(W2 + f * EH);
        #pragma unroll
        for (int k = 0; k < 16; ++k) {
            float4 w = w24[k];
            y += __shfl(z, 4*k,   64) * w.x + __shfl(z, 4*k+1, 64) * w.y
               + __shfl(z, 4*k+2, 64) * w.z + __shfl(z, 4*k+3, 64) * w.w;
        }
        Wt[(v << 10) + f] = y;                           // [v][i*32+o]
    } else if (t < TASK_VOCAB + TASK_PROJ) {
        int q = t - TASK_VOCAB;
        int n = q >> 5, o = q & 31;
        int gid = node_ids[n];
        const float4* nf4 = (const float4*)(node_table + (size_t)gid * NODE_INDIM);
        const float4* wr4 = (const float4*)(proj_W + o * NODE_INDIM);
        float acc = proj_b[o];
        #pragma unroll
        for (int j = 0; j < 16; ++j) {
            float4 a = nf4[j], b = wr4[j];
            acc += a.x*b.x + a.y*b.y + a.z*b.z + a.w*b.w;
        }
        float hval = fmaxf(acc, 0.f);
        h0[q] = hval;
        float c1 = hval * attn_w[o], c2 = hval * attn_w[32 + o];
        #pragma unroll
        for (int k = 16; k > 0; k >>= 1) {
            c1 += __shfl_xor(c1, k, 32);
            c2 += __shfl_xor(c2, k, 32);
        }
        if (o == 0) { ls[n] = c1; bs[n] = c2; }
    } else if (t < TASK_EDGE_BASE) {
        int q = t - (TASK_VOCAB + TASK_PROJ);            // q = j*32 + o
        int j = q >> 5, o = q & 31;
        Wpk4[q] = make_float4(gWih[o * 32 + j], gWih[(32 + o) * 32 + j],
                              gWih[(64 + o) * 32 + j], gWhh[o * 32 + j]);
        Wpk2[q] = make_float2(gWhh[(32 + o) * 32 + j], gWhh[(64 + o) * 32 + j]);
    } else {
        int e = t - TASK_EDGE_BASE;
        int d = dst[e];
        int blk = d >> 3;
        int pack = src[e] | (eid[e] << 14) | ((d & 7) << 20);
        int slot = atomicAdd(&cnt[blk], 1);
        if (slot < CAP) blkE[blk * CAP + slot] = pack;   // never overflows for this graph
    }
}

// ===========================================================================
// K2-4 mp: one kernel per step. Block owns 8 dst nodes + their bucketed edges.
//  edge phase: 8 edges/round, 32 lanes/edge (edge-parallel, latency hidden by
//              TLP) -> LDS msg/ex;  __syncthreads;
//  node phase: 8 node-groups reduce matching LDS entries, softmax-normalize,
//              relu, GRU, write h + next-step ls/bs. No atomics, no grid sync.
// ===========================================================================
__global__ __launch_bounds__(256)
void mp_kernel(const int* __restrict__ cnt, const int* __restrict__ blkE,
               const float* __restrict__ hc, const float* __restrict__ Wt,
               const float* __restrict__ attn_w,
               const float4* __restrict__ Wpk4, const float2* __restrict__ Wpk2,
               const float* __restrict__ gbih, const float* __restrict__ gbhh,
               const float* __restrict__ lsc, const float* __restrict__ bsc,
               float* __restrict__ lsn, float* __restrict__ bsn,
               float* __restrict__ op, int last)
{
    __shared__ float smsg[CAP][32];
    __shared__ float sexs[CAP];
    __shared__ int   spk[CAP];

    int b = blockIdx.x, tid = threadIdx.x;
    int cntB = cnt[b];
    if (cntB > CAP) cntB = CAP;
    if (tid < cntB) spk[tid] = blkE[b * CAP + tid];      // one coalesced preload
    __syncthreads();

    int g = tid >> 5, o = tid & 31;                      // 8 groups of 32 lanes

    // ---- edge phase: edge-parallel, 32 lanes per edge ----
    for (int eb = 0; eb < cntB; eb += 8) {
        int e = eb + g;
        if (e < cntB) {
            int pk = spk[e];
            int sp = pk & 0x3FFF, vid = (pk >> 14) & 0x3F, dl = pk >> 20;
            float a = lsc[sp] + bsc[(b << 3) + dl];      // logit: 2 scalar loads
            a = (a > 0.f) ? a : 0.01f * a;               // leaky_relu
            float ex = __expf(a);
            float hs = hc[(sp << 5) + o];
            const float* W = Wt + (vid << 10) + o;       // column o, coalesced rows
            float y0 = 0.f, y1 = 0.f, y2 = 0.f, y3 = 0.f;
            #pragma unroll
            for (int i = 0; i < 8; ++i) {
                y0 += __shfl(hs, 4*i,     32) * W[(4*i    ) * 32];
                y1 += __shfl(hs, 4*i + 1, 32) * W[(4*i + 1) * 32];
                y2 += __shfl(hs, 4*i + 2, 32) * W[(4*i + 2) * 32];
                y3 += __shfl(hs, 4*i + 3, 32) * W[(4*i + 3) * 32];
            }
            smsg[e][o] = ex * ((y0 + y1) + (y2 + y3));
            if (o == 0) sexs[e] = ex;
        }
    }
    __syncthreads();

    // ---- node phase: group g owns node (b*8+g) ----
    float sex = 0.f, acc = 0.f;
    for (int e = 0; e < cntB; ++e) {
        if ((spk[e] >> 20) == g) {                       // uniform within group
            acc += smsg[e][o];
            sex += sexs[e];
        }
    }
    float hv = hc[b * 256 + tid];                        // coalesced
    float m = (sex != 0.f) ? fmaxf(acc / sex, 0.f) : 0.f;

    // GRU cell (packed-transposed weights, L1-hot broadcast reads)
    float gir = 0.f, giz = 0.f, gin = 0.f, ghr = 0.f, ghz = 0.f, ghn = 0.f;
    #pragma unroll 4
    for (int j = 0; j < 32; ++j) {
        float mj = __shfl(m, j, 32);
        float hj = __shfl(hv, j, 32);
        float4 a4 = Wpk4[j * 32 + o];
        float2 b2 = Wpk2[j * 32 + o];
        gir += mj * a4.x;  giz += mj * a4.y;  gin += mj * a4.z;
        ghr += hj * a4.w;  ghz += hj * b2.x;  ghn += hj * b2.y;
    }
    float r  = 1.f / (1.f + __expf(-(gir + gbih[o]      + ghr + gbhh[o])));
    float z  = 1.f / (1.f + __expf(-(giz + gbih[32 + o] + ghz + gbhh[32 + o])));
    float nn = tanhf(gin + gbih[64 + o] + r * (ghn + gbhh[64 + o]));
    float hid = (1.f - z) * nn + z * hv;
    op[b * 256 + tid] = hid;

    if (!last) {                                         // next step's attention scalars
        float c1 = hid * attn_w[o], c2 = hid * attn_w[32 + o];
        #pragma unroll
        for (int k = 16; k > 0; k >>= 1) {
            c1 += __shfl_xor(c1, k, 32);
            c2 += __shfl_xor(c2, k, 32);
        }
        if (o == 0) { lsn[(b << 3) + g] = c1; bsn[(b << 3) + g] = c2; }
    }
}

// ===========================================================================
extern "C" void kernel_launch(void* const* d_in, const int* in_sizes, int n_in,
                              void* d_out, int out_size, void* d_ws, size_t ws_size,
                              hipStream_t stream) {
    const int*   node_ids   = (const int*)d_in[0];
    const int*   edge_ids   = (const int*)d_in[1];
    const int*   srcp       = (const int*)d_in[2];
    const int*   dstp       = (const int*)d_in[3];
    const float* node_table = (const float*)d_in[4];
    const float* edge_table = (const float*)d_in[5];
    const float* proj_W     = (const float*)d_in[6];
    const float* proj_b     = (const float*)d_in[7];
    const float* attn_w     = (const float*)d_in[8];
    const float* e1_W1 = (const float*)d_in[9];  const float* e1_b1 = (const float*)d_in[10];
    const float* e1_W2 = (const float*)d_in[11]; const float* e1_b2 = (const float*)d_in[12];
    const float* e2_W1 = (const float*)d_in[13]; const float* e2_b1 = (const float*)d_in[14];
    const float* e2_W2 = (const float*)d_in[15]; const float* e2_b2 = (const float*)d_in[16];
    const float* gWih  = (const float*)d_in[17]; const float* gWhh  = (const float*)d_in[18];
    const float* gbih  = (const float*)d_in[19]; const float* gbhh  = (const float*)d_in[20];
    float* outp = (float*)d_out;

    char* ws = (char*)d_ws;
    float*  Wt   = (float*)(ws + WT_OFF);
    float*  h0b  = (float*)(ws + H0_OFF);
    float*  h1b  = (float*)(ws + H1_OFF);
    float4* Wpk4 = (float4*)(ws + W4_OFF);
    float2* Wpk2 = (float2*)(ws + W2_OFF);
    float*  ls0  = (float*)(ws + LS0_OFF);
    float*  bs0  = (float*)(ws + BS0_OFF);
    float*  ls1  = (float*)(ws + LS1_OFF);
    float*  bs1  = (float*)(ws + BS1_OFF);
    int*    cnt  = (int*)  (ws + CNT_OFF);
    int*    blkE = (int*)  (ws + EPK_OFF);

    // zero per-block edge counters only (graph-capture-safe)
    hipMemsetAsync(ws + CNT_OFF, 0, 7680, stream);

    setup_kernel<<<(TA_TOTAL + 255) / 256, 256, 0, stream>>>(
        node_ids, srcp, dstp, edge_ids, node_table, edge_table, proj_W, proj_b,
        attn_w, e1_W1, e1_b1, e1_W2, e1_b2, e2_W1, e2_b1, e2_W2, e2_b2,
        gWih, gWhh, Wt, h0b, ls0, bs0, Wpk4, Wpk2, cnt, blkE);

    float* hc = h0b;  float* hn = h1b;
    float* lc = ls0;  float* bc = bs0;
    float* ln = ls1;  float* bn = bs1;
    for (int step = 0; step < 3; ++step) {
        int last = (step == 2);
        float* op = last ? outp : hn;
        mp_kernel<<<NBLK, 256, 0, stream>>>(
            cnt, blkE, hc, Wt, attn_w, Wpk4, Wpk2, gbih, gbhh,
            lc, bc, ln, bn, op, last);
        float* tf;
        tf = hc; hc = hn; hn = tf;
        tf = lc; lc = ln; ln = tf;
        tf = bc; bc = bn; bn = tf;
    }
}

// Round 5
// 219.117 us; speedup vs baseline: 3.5341x; 1.0062x over previous
//
#include <hip/hip_runtime.h>
#include <math.h>

#define N_NODES   15000
#define N_EDGES   60000
#define EVOCAB    54
#define NODE_INDIM 64
#define EDGE_INDIM 32
#define H  32
#define EH 64
#define N_BOND 4

#define NPB   8          // nodes per block (15000/8 = 1875 blocks exact)
#define NBLK  (N_NODES / NPB)            // 1875
#define CAP   128        // per-block edge capacity (avg 32, P[Poisson(32)>128]~1e-40)

// ---- setup task layout (segment bases 64-aligned so shfl groups never straddle) ----
#define TASK_VOCAB (EVOCAB * 1024)                 // 55296
#define TASK_PROJ  (N_NODES * H)                   // 480000
#define TASK_PACK  (H * H)                         // 1024
#define TASK_EDGE_BASE (TASK_VOCAB + TASK_PROJ + TASK_PACK)  // 536320
#define TA_TOTAL   (TASK_EDGE_BASE + N_EDGES)                // 596320

// ---- workspace offsets (bytes) ----
#define WT_OFF  0          // 221184  vocab weight table [54][1024]
#define H0_OFF  221184     // 1920000
#define H1_OFF  2141184    // 1920000
#define W4_OFF  4061184    // 16384   GRU packed float4
#define W2_OFF  4077568    // 8192    GRU packed float2
#define LS0_OFF 4085760    // 60000   per-node src-logit (pairs h0)
#define BS0_OFF 4145760    // 60000   per-node dst-logit (pairs h0)
#define LS1_OFF 4205760    // 60000
#define BS1_OFF 4265760    // 60000
#define CNT_OFF 4325760    // 7680    per-block edge counters (memset 0)
#define EPK_OFF 4333440    // 960000  bucketed packed edges [1875][128]

// ===========================================================================
// K1 setup: vocab Wt | h0 projection (+ls0/bs0) | GRU pack | edge bucketing.
// Edge pack: src(14b) | vid(6b)<<14 | dstlocal(3b)<<20, bucket = dst>>3.
// ===========================================================================
__global__ __launch_bounds__(256)
void setup_kernel(const int* __restrict__ node_ids, const int* __restrict__ src,
                  const int* __restrict__ dst, const int* __restrict__ eid,
                  const float* __restrict__ node_table, const float* __restrict__ edge_table,
                  const float* __restrict__ proj_W, const float* __restrict__ proj_b,
                  const float* __restrict__ attn_w,
                  const float* __restrict__ e1_W1, const float* __restrict__ e1_b1,
                  const float* __restrict__ e1_W2, const float* __restrict__ e1_b2,
                  const float* __restrict__ e2_W1, const float* __restrict__ e2_b1,
                  const float* __restrict__ e2_W2, const float* __restrict__ e2_b2,
                  const float* __restrict__ gWih, const float* __restrict__ gWhh,
                  float* __restrict__ Wt, float* __restrict__ h0,
                  float* __restrict__ ls, float* __restrict__ bs,
                  float4* __restrict__ Wpk4, float2* __restrict__ Wpk2,
                  int* __restrict__ cnt, int* __restrict__ blkE)
{
    int t = blockIdx.x * 256 + threadIdx.x;
    if (t >= TA_TOTAL) return;
    if (t < TASK_VOCAB) {
        int v = t >> 10, f = t & 1023, l = t & 63;       // v wave-uniform
        const float* W1 = (v < N_BOND) ? e1_W1 : e2_W1;
        const float* b1 = (v < N_BOND) ? e1_b1 : e2_b1;
        const float* W2 = (v < N_BOND) ? e1_W2 : e2_W2;
        const float* b2 = (v < N_BOND) ? e1_b2 : e2_b2;
        const float4* ef4 = (const float4*)(edge_table + v * EDGE_INDIM);
        const float4* w14 = (const float4*)(W1 + l * EDGE_INDIM);
        float z = b1[l];
        #pragma unroll
        for (int j = 0; j < 8; ++j) {
            float4 a = ef4[j], b = w14[j];
            z += a.x*b.x + a.y*b.y + a.z*b.z + a.w*b.w;
        }
        z = fmaxf(z, 0.f);
        float y = b2[f];
        const float4* w24 = (const float4*)(W2 + f * EH);
        #pragma unroll
        for (int k = 0; k < 16; ++k) {
            float4 w = w24[k];
            y += __shfl(z, 4*k,   64) * w.x + __shfl(z, 4*k+1, 64) * w.y
               + __shfl(z, 4*k+2, 64) * w.z + __shfl(z, 4*k+3, 64) * w.w;
        }
        Wt[(v << 10) + f] = y;                           // [v][i*32+o]
    } else if (t < TASK_VOCAB + TASK_PROJ) {
        int q = t - TASK_VOCAB;
        int n = q >> 5, o = q & 31;
        int gid = node_ids[n];
        const float4* nf4 = (const float4*)(node_table + (size_t)gid * NODE_INDIM);
        const float4* wr4 = (const float4*)(proj_W + o * NODE_INDIM);
        float acc = proj_b[o];
        #pragma unroll
        for (int j = 0; j < 16; ++j) {
            float4 a = nf4[j], b = wr4[j];
            acc += a.x*b.x + a.y*b.y + a.z*b.z + a.w*b.w;
        }
        float hval = fmaxf(acc, 0.f);
        h0[q] = hval;
        float c1 = hval * attn_w[o], c2 = hval * attn_w[32 + o];
        #pragma unroll
        for (int k = 16; k > 0; k >>= 1) {
            c1 += __shfl_xor(c1, k, 32);
            c2 += __shfl_xor(c2, k, 32);
        }
        if (o == 0) { ls[n] = c1; bs[n] = c2; }
    } else if (t < TASK_EDGE_BASE) {
        int q = t - (TASK_VOCAB + TASK_PROJ);            // q = j*32 + o
        int j = q >> 5, o = q & 31;
        Wpk4[q] = make_float4(gWih[o * 32 + j], gWih[(32 + o) * 32 + j],
                              gWih[(64 + o) * 32 + j], gWhh[o * 32 + j]);
        Wpk2[q] = make_float2(gWhh[(32 + o) * 32 + j], gWhh[(64 + o) * 32 + j]);
    } else {
        int e = t - TASK_EDGE_BASE;
        int d = dst[e];
        int blk = d >> 3;
        int pack = src[e] | (eid[e] << 14) | ((d & 7) << 20);
        int slot = atomicAdd(&cnt[blk], 1);
        if (slot < CAP) blkE[blk * CAP + slot] = pack;   // never overflows for this graph
    }
}

// ===========================================================================
// K2-4 mp: block owns 8 dst nodes + bucketed edges.
//  edge phase: 8 groups x 2 edges in flight (eb += 16), float4 W-matvec:
//    lane o loads W4[k*32+o] (8 dwordx4, coalesced), partial float4 over rows
//    i=4k+(o>>3) via variable-lane shfl of hs, butterfly xor(8,16) reduce,
//    lanes 0-7 ds_write_b128 the weighted message. No atomics.
//  node phase: group g reduces its node's LDS entries, softmax-normalize,
//    relu, GRU, write h + next-step ls/bs.
// ===========================================================================
__global__ __launch_bounds__(256)
void mp_kernel(const int* __restrict__ cnt, const int* __restrict__ blkE,
               const float* __restrict__ hc, const float* __restrict__ Wt,
               const float* __restrict__ attn_w,
               const float4* __restrict__ Wpk4, const float2* __restrict__ Wpk2,
               const float* __restrict__ gbih, const float* __restrict__ gbhh,
               const float* __restrict__ lsc, const float* __restrict__ bsc,
               float* __restrict__ lsn, float* __restrict__ bsn,
               float* __restrict__ op, int last)
{
    __shared__ float4 smsg4[CAP * 8];                    // [e][8] float4 = [e][32] float
    __shared__ float  sexs[CAP];
    __shared__ int    spk[CAP];
    __shared__ float  sbs[NPB];

    int b = blockIdx.x, tid = threadIdx.x;
    int cntB = cnt[b];
    if (cntB > CAP) cntB = CAP;
    if (tid < cntB) spk[tid] = blkE[b * CAP + tid];      // one coalesced preload
    if (tid < NPB)  sbs[tid] = bsc[(b << 3) + tid];
    __syncthreads();

    int g = tid >> 5, o = tid & 31;                      // 8 groups of 32 lanes

    // ---- edge phase: 2 independent edges per group per iteration ----
    for (int eb = 0; eb < cntB; eb += 16) {
        int e0 = eb + g, e1 = eb + 8 + g;
        // edge 0
        float ex0 = 0.f; float4 p0 = make_float4(0.f, 0.f, 0.f, 0.f);
        if (e0 < cntB) {
            int pk = spk[e0];
            int sp = pk & 0x3FFF, vid = (pk >> 14) & 0x3F, dl = pk >> 20;
            float a = lsc[sp] + sbs[dl];
            a = (a > 0.f) ? a : 0.01f * a;
            ex0 = __expf(a);
            float hs = hc[(sp << 5) + o];
            const float4* W4 = (const float4*)(Wt + (vid << 10));
            #pragma unroll
            for (int k = 0; k < 8; ++k) {
                float4 w = W4[k * 32 + o];
                float hsk = __shfl(hs, 4 * k + (o >> 3), 32);
                p0.x += hsk * w.x; p0.y += hsk * w.y;
                p0.z += hsk * w.z; p0.w += hsk * w.w;
            }
        }
        // edge 1
        float ex1 = 0.f; float4 p1 = make_float4(0.f, 0.f, 0.f, 0.f);
        if (e1 < cntB) {
            int pk = spk[e1];
            int sp = pk & 0x3FFF, vid = (pk >> 14) & 0x3F, dl = pk >> 20;
            float a = lsc[sp] + sbs[dl];
            a = (a > 0.f) ? a : 0.01f * a;
            ex1 = __expf(a);
            float hs = hc[(sp << 5) + o];
            const float4* W4 = (const float4*)(Wt + (vid << 10));
            #pragma unroll
            for (int k = 0; k < 8; ++k) {
                float4 w = W4[k * 32 + o];
                float hsk = __shfl(hs, 4 * k + (o >> 3), 32);
                p1.x += hsk * w.x; p1.y += hsk * w.y;
                p1.z += hsk * w.z; p1.w += hsk * w.w;
            }
        }
        // butterfly reduce across lanes {o, o^8, o^16, o^24}
        p0.x += __shfl_xor(p0.x, 8, 32);  p0.y += __shfl_xor(p0.y, 8, 32);
        p0.z += __shfl_xor(p0.z, 8, 32);  p0.w += __shfl_xor(p0.w, 8, 32);
        p0.x += __shfl_xor(p0.x, 16, 32); p0.y += __shfl_xor(p0.y, 16, 32);
        p0.z += __shfl_xor(p0.z, 16, 32); p0.w += __shfl_xor(p0.w, 16, 32);
        p1.x += __shfl_xor(p1.x, 8, 32);  p1.y += __shfl_xor(p1.y, 8, 32);
        p1.z += __shfl_xor(p1.z, 8, 32);  p1.w += __shfl_xor(p1.w, 8, 32);
        p1.x += __shfl_xor(p1.x, 16, 32); p1.y += __shfl_xor(p1.y, 16, 32);
        p1.z += __shfl_xor(p1.z, 16, 32); p1.w += __shfl_xor(p1.w, 16, 32);
        if (e0 < cntB && o < 8) {
            smsg4[e0 * 8 + o] = make_float4(ex0 * p0.x, ex0 * p0.y, ex0 * p0.z, ex0 * p0.w);
            if (o == 0) sexs[e0] = ex0;
        }
        if (e1 < cntB && o < 8) {
            smsg4[e1 * 8 + o] = make_float4(ex1 * p1.x, ex1 * p1.y, ex1 * p1.z, ex1 * p1.w);
            if (o == 0) sexs[e1] = ex1;
        }
    }
    __syncthreads();

    // ---- node phase: group g owns node (b*8+g) ----
    const float* smsg = (const float*)smsg4;
    float sex = 0.f, acc = 0.f;
    for (int e = 0; e < cntB; ++e) {
        if ((spk[e] >> 20) == g) {                       // uniform within group
            acc += smsg[e * 32 + o];
            sex += sexs[e];
        }
    }
    float hv = hc[b * 256 + tid];                        // coalesced
    float m = (sex != 0.f) ? fmaxf(acc / sex, 0.f) : 0.f;

    // GRU cell (packed-transposed weights, L1-hot broadcast reads)
    float gir = 0.f, giz = 0.f, gin = 0.f, ghr = 0.f, ghz = 0.f, ghn = 0.f;
    #pragma unroll 4
    for (int j = 0; j < 32; ++j) {
        float mj = __shfl(m, j, 32);
        float hj = __shfl(hv, j, 32);
        float4 a4 = Wpk4[j * 32 + o];
        float2 b2 = Wpk2[j * 32 + o];
        gir += mj * a4.x;  giz += mj * a4.y;  gin += mj * a4.z;
        ghr += hj * a4.w;  ghz += hj * b2.x;  ghn += hj * b2.y;
    }
    float r  = 1.f / (1.f + __expf(-(gir + gbih[o]      + ghr + gbhh[o])));
    float z  = 1.f / (1.f + __expf(-(giz + gbih[32 + o] + ghz + gbhh[32 + o])));
    float nn = tanhf(gin + gbih[64 + o] + r * (ghn + gbhh[64 + o]));
    float hid = (1.f - z) * nn + z * hv;
    op[b * 256 + tid] = hid;

    if (!last) {                                         // next step's attention scalars
        float c1 = hid * attn_w[o], c2 = hid * attn_w[32 + o];
        #pragma unroll
        for (int k = 16; k > 0; k >>= 1) {
            c1 += __shfl_xor(c1, k, 32);
            c2 += __shfl_xor(c2, k, 32);
        }
        if (o == 0) { lsn[(b << 3) + g] = c1; bsn[(b << 3) + g] = c2; }
    }
}

// ===========================================================================
extern "C" void kernel_launch(void* const* d_in, const int* in_sizes, int n_in,
                              void* d_out, int out_size, void* d_ws, size_t ws_size,
                              hipStream_t stream) {
    const int*   node_ids   = (const int*)d_in[0];
    const int*   edge_ids   = (const int*)d_in[1];
    const int*   srcp       = (const int*)d_in[2];
    const int*   dstp       = (const int*)d_in[3];
    const float* node_table = (const float*)d_in[4];
    const float* edge_table = (const float*)d_in[5];
    const float* proj_W     = (const float*)d_in[6];
    const float* proj_b     = (const float*)d_in[7];
    const float* attn_w     = (const float*)d_in[8];
    const float* e1_W1 = (const float*)d_in[9];  const float* e1_b1 = (const float*)d_in[10];
    const float* e1_W2 = (const float*)d_in[11]; const float* e1_b2 = (const float*)d_in[12];
    const float* e2_W1 = (const float*)d_in[13]; const float* e2_b1 = (const float*)d_in[14];
    const float* e2_W2 = (const float*)d_in[15]; const float* e2_b2 = (const float*)d_in[16];
    const float* gWih  = (const float*)d_in[17]; const float* gWhh  = (const float*)d_in[18];
    const float* gbih  = (const float*)d_in[19]; const float* gbhh  = (const float*)d_in[20];
    float* outp = (float*)d_out;

    char* ws = (char*)d_ws;
    float*  Wt   = (float*)(ws + WT_OFF);
    float*  h0b  = (float*)(ws + H0_OFF);
    float*  h1b  = (float*)(ws + H1_OFF);
    float4* Wpk4 = (float4*)(ws + W4_OFF);
    float2* Wpk2 = (float2*)(ws + W2_OFF);
    float*  ls0  = (float*)(ws + LS0_OFF);
    float*  bs0  = (float*)(ws + BS0_OFF);
    float*  ls1  = (float*)(ws + LS1_OFF);
    float*  bs1  = (float*)(ws + BS1_OFF);
    int*    cnt  = (int*)  (ws + CNT_OFF);
    int*    blkE = (int*)  (ws + EPK_OFF);

    // zero per-block edge counters only (graph-capture-safe)
    hipMemsetAsync(ws + CNT_OFF, 0, 7680, stream);

    setup_kernel<<<(TA_TOTAL + 255) / 256, 256, 0, stream>>>(
        node_ids, srcp, dstp, edge_ids, node_table, edge_table, proj_W, proj_b,
        attn_w, e1_W1, e1_b1, e1_W2, e1_b2, e2_W1, e2_b1, e2_W2, e2_b2,
        gWih, gWhh, Wt, h0b, ls0, bs0, Wpk4, Wpk2, cnt, blkE);

    float* hc = h0b;  float* hn = h1b;
    float* lc = ls0;  float* bc = bs0;
    float* ln = ls1;  float* bn = bs1;
    for (int step = 0; step < 3; ++step) {
        int last = (step == 2);
        float* op = last ? outp : hn;
        mp_kernel<<<NBLK, 256, 0, stream>>>(
            cnt, blkE, hc, Wt, attn_w, Wpk4, Wpk2, gbih, gbhh,
            lc, bc, ln, bn, op, last);
        float* tf;
        tf = hc; hc = hn; hn = tf;
        tf = lc; lc = ln; ln = tf;
        tf = bc; bc = bn; bn = tf;
    }
}

// Round 6
// 209.779 us; speedup vs baseline: 3.6915x; 1.0445x over previous
//
#include <hip/hip_runtime.h>
#include <math.h>

#define N_NODES   15000
#define N_EDGES   60000
#define EVOCAB    54
#define NODE_INDIM 64
#define EDGE_INDIM 32
#define H  32
#define EH 64
#define N_BOND 4

#define NPB   8          // nodes per block (15000/8 = 1875 blocks exact)
#define NBLK  (N_NODES / NPB)            // 1875
#define CAP   128        // per-block edge capacity (avg 32, P[Poisson(32)>128]~1e-40)

// ---- setup task layout (segment bases 64-aligned so shfl groups never straddle) ----
#define TASK_VOCAB (EVOCAB * 1024)                 // 55296
#define TASK_PROJ  (N_NODES * H)                   // 480000
#define TASK_EDGE_BASE (TASK_VOCAB + TASK_PROJ)    // 535296 (64-aligned)
#define TA_TOTAL   (TASK_EDGE_BASE + N_EDGES)      // 595296

// ---- workspace offsets (bytes) ----
#define WT_OFF   0          // 221184  vocab weight table [54][1024]
#define H0_OFF   221184     // 1920000
#define H1_OFF   2141184    // 1920000
#define W4_OFF   4061184    // 16384   GRU packed float4
#define W2_OFF   4077568    // 8192    GRU packed float2
#define LS0_OFF  4085760    // 60000   per-node src-logit (pairs h0)
#define BS0_OFF  4145760    // 60000   per-node dst-logit (pairs h0)
#define LS1_OFF  4205760    // 60000
#define BS1_OFF  4265760    // 60000
#define CNT_OFF  4325760    // 7680    per-block edge counters (zeroed by pre_kernel)
#define EPK_OFF  4333440    // 960000  bucketed packed edges [1875][128]
#define W2T1_OFF 5293440    // 262144  e1_W2 transposed [64][1024]
#define W2T2_OFF 5555584    // 262144  e2_W2 transposed [64][1024]
#define PT_OFF   5817728    // 8192    proj_W transposed [64][32]

// ===========================================================================
// K0 pre: weight transposes (coalesced via LDS tiles) + GRU pack + cnt zero.
// Replaces the old hipMemsetAsync dispatch — dispatch count unchanged.
//  blocks 0-31 : W2 transpose tiles (16 per table), [1024][64] -> [64][1024]
//  block  32   : proj_W transpose [32][64] -> PT[j*32+o]
//  blocks 33-36: GRU weight pack (as before)
//  block  37   : zero cnt
// ===========================================================================
__global__ __launch_bounds__(256)
void pre_kernel(const float* __restrict__ e1_W2, const float* __restrict__ e2_W2,
                const float* __restrict__ proj_W,
                const float* __restrict__ gWih, const float* __restrict__ gWhh,
                float* __restrict__ W2T1, float* __restrict__ W2T2,
                float* __restrict__ PT,
                float4* __restrict__ Wpk4, float2* __restrict__ Wpk2,
                int* __restrict__ cnt)
{
    int b = blockIdx.x, tid = threadIdx.x;
    if (b < 32) {
        __shared__ float st[64][65];                 // +1 pad: conflict-free both phases
        const float* in = (b < 16) ? e1_W2 : e2_W2;
        float* out      = (b < 16) ? W2T1  : W2T2;
        int f0 = (b & 15) * 64;
        #pragma unroll
        for (int it = 0; it < 16; ++it) {
            int idx = it * 256 + tid;                // 0..4095
            int r = idx >> 6, c = idx & 63;
            st[r][c] = in[(f0 + r) * 64 + c];        // read coalesced
        }
        __syncthreads();
        #pragma unroll
        for (int it = 0; it < 16; ++it) {
            int idx = it * 256 + tid;
            int k = idx >> 6, f = idx & 63;
            out[k * 1024 + f0 + f] = st[f][k];       // write coalesced
        }
    } else if (b == 32) {
        __shared__ float sp2[64][33];
        #pragma unroll
        for (int it = 0; it < 8; ++it) {
            int idx = it * 256 + tid;                // 0..2047
            int o = idx >> 6, j = idx & 63;
            sp2[j][o] = proj_W[idx];                 // read coalesced
        }
        __syncthreads();
        #pragma unroll
        for (int it = 0; it < 8; ++it) {
            int idx = it * 256 + tid;
            int j = idx >> 5, o = idx & 31;
            PT[idx] = sp2[j][o];                     // write coalesced
        }
    } else if (b <= 36) {
        int q = (b - 33) * 256 + tid;                // q = j*32 + o < 1024
        int j = q >> 5, o = q & 31;
        Wpk4[q] = make_float4(gWih[o * 32 + j], gWih[(32 + o) * 32 + j],
                              gWih[(64 + o) * 32 + j], gWhh[o * 32 + j]);
        Wpk2[q] = make_float2(gWhh[(32 + o) * 32 + j], gWhh[(64 + o) * 32 + j]);
    } else {
        #pragma unroll
        for (int it = 0; it < 8; ++it) {
            int idx = it * 256 + tid;
            if (idx < NBLK) cnt[idx] = 0;
        }
    }
}

// ===========================================================================
// K1 setup: vocab Wt (coalesced via W2T) | h0 projection (coalesced via PT,
//           +ls0/bs0 attention scalars) | edge bucketing.
// Edge pack: src(14b) | vid(6b)<<14 | dstlocal(3b)<<20, bucket = dst>>3.
// ===========================================================================
__global__ __launch_bounds__(256)
void setup_kernel(const int* __restrict__ node_ids, const int* __restrict__ src,
                  const int* __restrict__ dst, const int* __restrict__ eid,
                  const float* __restrict__ node_table, const float* __restrict__ edge_table,
                  const float* __restrict__ PT, const float* __restrict__ proj_b,
                  const float* __restrict__ attn_w,
                  const float* __restrict__ e1_W1, const float* __restrict__ e1_b1,
                  const float* __restrict__ e1_b2,
                  const float* __restrict__ e2_W1, const float* __restrict__ e2_b1,
                  const float* __restrict__ e2_b2,
                  const float* __restrict__ W2T1, const float* __restrict__ W2T2,
                  float* __restrict__ Wt, float* __restrict__ h0,
                  float* __restrict__ ls, float* __restrict__ bs,
                  int* __restrict__ cnt, int* __restrict__ blkE)
{
    int t = blockIdx.x * 256 + threadIdx.x;
    if (t >= TA_TOTAL) return;
    if (t < TASK_VOCAB) {
        int v = t >> 10, f = t & 1023, l = t & 63;       // v wave-uniform
        const float* W1  = (v < N_BOND) ? e1_W1 : e2_W1;
        const float* b1  = (v < N_BOND) ? e1_b1 : e2_b1;
        const float* b2  = (v < N_BOND) ? e1_b2 : e2_b2;
        const float* W2T = (v < N_BOND) ? W2T1  : W2T2;
        const float4* ef4 = (const float4*)(edge_table + v * EDGE_INDIM);
        const float4* w14 = (const float4*)(W1 + l * EDGE_INDIM);
        float z = b1[l];
        #pragma unroll
        for (int j = 0; j < 8; ++j) {
            float4 a = ef4[j], b = w14[j];
            z += a.x*b.x + a.y*b.y + a.z*b.z + a.w*b.w;
        }
        z = fmaxf(z, 0.f);
        float y = b2[f];
        #pragma unroll 16
        for (int k = 0; k < 64; ++k)                     // coalesced 256B per k
            y += __shfl(z, k, 64) * W2T[k * 1024 + f];
        Wt[(v << 10) + f] = y;                           // [v][i*32+o]
    } else if (t < TASK_EDGE_BASE) {
        int q = t - TASK_VOCAB;
        int n = q >> 5, o = q & 31;
        int gid = node_ids[n];
        const float* nf = node_table + (size_t)gid * NODE_INDIM;
        float nfa = nf[o], nfb = nf[32 + o];             // 2 coalesced row reads
        float acc = proj_b[o];
        #pragma unroll 8
        for (int j = 0; j < 32; ++j)                     // PT: 128B coalesced, L1-hot
            acc += __shfl(nfa, j, 32) * PT[j * 32 + o];
        #pragma unroll 8
        for (int j = 0; j < 32; ++j)
            acc += __shfl(nfb, j, 32) * PT[(32 + j) * 32 + o];
        float hval = fmaxf(acc, 0.f);
        h0[q] = hval;
        float c1 = hval * attn_w[o], c2 = hval * attn_w[32 + o];
        #pragma unroll
        for (int k = 16; k > 0; k >>= 1) {
            c1 += __shfl_xor(c1, k, 32);
            c2 += __shfl_xor(c2, k, 32);
        }
        if (o == 0) { ls[n] = c1; bs[n] = c2; }
    } else {
        int e = t - TASK_EDGE_BASE;
        int d = dst[e];
        int blk = d >> 3;
        int pack = src[e] | (eid[e] << 14) | ((d & 7) << 20);
        int slot = atomicAdd(&cnt[blk], 1);
        if (slot < CAP) blkE[blk * CAP + slot] = pack;   // never overflows for this graph
    }
}

// ===========================================================================
// K2-4 mp: unchanged from round-5 known-good (219 us). Block owns 8 dst nodes
// + bucketed edges; edge phase 2-deep float4 matvec -> LDS; node phase
// segment-reduce + softmax + GRU. No atomics, no grid sync.
// ===========================================================================
__global__ __launch_bounds__(256)
void mp_kernel(const int* __restrict__ cnt, const int* __restrict__ blkE,
               const float* __restrict__ hc, const float* __restrict__ Wt,
               const float* __restrict__ attn_w,
               const float4* __restrict__ Wpk4, const float2* __restrict__ Wpk2,
               const float* __restrict__ gbih, const float* __restrict__ gbhh,
               const float* __restrict__ lsc, const float* __restrict__ bsc,
               float* __restrict__ lsn, float* __restrict__ bsn,
               float* __restrict__ op, int last)
{
    __shared__ float4 smsg4[CAP * 8];                    // [e][8] float4 = [e][32] float
    __shared__ float  sexs[CAP];
    __shared__ int    spk[CAP];
    __shared__ float  sbs[NPB];

    int b = blockIdx.x, tid = threadIdx.x;
    int cntB = cnt[b];
    if (cntB > CAP) cntB = CAP;
    if (tid < cntB) spk[tid] = blkE[b * CAP + tid];      // one coalesced preload
    if (tid < NPB)  sbs[tid] = bsc[(b << 3) + tid];
    __syncthreads();

    int g = tid >> 5, o = tid & 31;                      // 8 groups of 32 lanes

    // ---- edge phase: 2 independent edges per group per iteration ----
    for (int eb = 0; eb < cntB; eb += 16) {
        int e0 = eb + g, e1 = eb + 8 + g;
        float ex0 = 0.f; float4 p0 = make_float4(0.f, 0.f, 0.f, 0.f);
        if (e0 < cntB) {
            int pk = spk[e0];
            int sp = pk & 0x3FFF, vid = (pk >> 14) & 0x3F, dl = pk >> 20;
            float a = lsc[sp] + sbs[dl];
            a = (a > 0.f) ? a : 0.01f * a;
            ex0 = __expf(a);
            float hs = hc[(sp << 5) + o];
            const float4* W4 = (const float4*)(Wt + (vid << 10));
            #pragma unroll
            for (int k = 0; k < 8; ++k) {
                float4 w = W4[k * 32 + o];
                float hsk = __shfl(hs, 4 * k + (o >> 3), 32);
                p0.x += hsk * w.x; p0.y += hsk * w.y;
                p0.z += hsk * w.z; p0.w += hsk * w.w;
            }
        }
        float ex1 = 0.f; float4 p1 = make_float4(0.f, 0.f, 0.f, 0.f);
        if (e1 < cntB) {
            int pk = spk[e1];
            int sp = pk & 0x3FFF, vid = (pk >> 14) & 0x3F, dl = pk >> 20;
            float a = lsc[sp] + sbs[dl];
            a = (a > 0.f) ? a : 0.01f * a;
            ex1 = __expf(a);
            float hs = hc[(sp << 5) + o];
            const float4* W4 = (const float4*)(Wt + (vid << 10));
            #pragma unroll
            for (int k = 0; k < 8; ++k) {
                float4 w = W4[k * 32 + o];
                float hsk = __shfl(hs, 4 * k + (o >> 3), 32);
                p1.x += hsk * w.x; p1.y += hsk * w.y;
                p1.z += hsk * w.z; p1.w += hsk * w.w;
            }
        }
        p0.x += __shfl_xor(p0.x, 8, 32);  p0.y += __shfl_xor(p0.y, 8, 32);
        p0.z += __shfl_xor(p0.z, 8, 32);  p0.w += __shfl_xor(p0.w, 8, 32);
        p0.x += __shfl_xor(p0.x, 16, 32); p0.y += __shfl_xor(p0.y, 16, 32);
        p0.z += __shfl_xor(p0.z, 16, 32); p0.w += __shfl_xor(p0.w, 16, 32);
        p1.x += __shfl_xor(p1.x, 8, 32);  p1.y += __shfl_xor(p1.y, 8, 32);
        p1.z += __shfl_xor(p1.z, 8, 32);  p1.w += __shfl_xor(p1.w, 8, 32);
        p1.x += __shfl_xor(p1.x, 16, 32); p1.y += __shfl_xor(p1.y, 16, 32);
        p1.z += __shfl_xor(p1.z, 16, 32); p1.w += __shfl_xor(p1.w, 16, 32);
        if (e0 < cntB && o < 8) {
            smsg4[e0 * 8 + o] = make_float4(ex0 * p0.x, ex0 * p0.y, ex0 * p0.z, ex0 * p0.w);
            if (o == 0) sexs[e0] = ex0;
        }
        if (e1 < cntB && o < 8) {
            smsg4[e1 * 8 + o] = make_float4(ex1 * p1.x, ex1 * p1.y, ex1 * p1.z, ex1 * p1.w);
            if (o == 0) sexs[e1] = ex1;
        }
    }
    __syncthreads();

    // ---- node phase: group g owns node (b*8+g) ----
    const float* smsg = (const float*)smsg4;
    float sex = 0.f, acc = 0.f;
    for (int e = 0; e < cntB; ++e) {
        if ((spk[e] >> 20) == g) {                       // uniform within group
            acc += smsg[e * 32 + o];
            sex += sexs[e];
        }
    }
    float hv = hc[b * 256 + tid];                        // coalesced
    float m = (sex != 0.f) ? fmaxf(acc / sex, 0.f) : 0.f;

    float gir = 0.f, giz = 0.f, gin = 0.f, ghr = 0.f, ghz = 0.f, ghn = 0.f;
    #pragma unroll 4
    for (int j = 0; j < 32; ++j) {
        float mj = __shfl(m, j, 32);
        float hj = __shfl(hv, j, 32);
        float4 a4 = Wpk4[j * 32 + o];
        float2 b2 = Wpk2[j * 32 + o];
        gir += mj * a4.x;  giz += mj * a4.y;  gin += mj * a4.z;
        ghr += hj * a4.w;  ghz += hj * b2.x;  ghn += hj * b2.y;
    }
    float r  = 1.f / (1.f + __expf(-(gir + gbih[o]      + ghr + gbhh[o])));
    float z  = 1.f / (1.f + __expf(-(giz + gbih[32 + o] + ghz + gbhh[32 + o])));
    float nn = tanhf(gin + gbih[64 + o] + r * (ghn + gbhh[64 + o]));
    float hid = (1.f - z) * nn + z * hv;
    op[b * 256 + tid] = hid;

    if (!last) {                                         // next step's attention scalars
        float c1 = hid * attn_w[o], c2 = hid * attn_w[32 + o];
        #pragma unroll
        for (int k = 16; k > 0; k >>= 1) {
            c1 += __shfl_xor(c1, k, 32);
            c2 += __shfl_xor(c2, k, 32);
        }
        if (o == 0) { lsn[(b << 3) + g] = c1; bsn[(b << 3) + g] = c2; }
    }
}

// ===========================================================================
extern "C" void kernel_launch(void* const* d_in, const int* in_sizes, int n_in,
                              void* d_out, int out_size, void* d_ws, size_t ws_size,
                              hipStream_t stream) {
    const int*   node_ids   = (const int*)d_in[0];
    const int*   edge_ids   = (const int*)d_in[1];
    const int*   srcp       = (const int*)d_in[2];
    const int*   dstp       = (const int*)d_in[3];
    const float* node_table = (const float*)d_in[4];
    const float* edge_table = (const float*)d_in[5];
    const float* proj_W     = (const float*)d_in[6];
    const float* proj_b     = (const float*)d_in[7];
    const float* attn_w     = (const float*)d_in[8];
    const float* e1_W1 = (const float*)d_in[9];  const float* e1_b1 = (const float*)d_in[10];
    const float* e1_W2 = (const float*)d_in[11]; const float* e1_b2 = (const float*)d_in[12];
    const float* e2_W1 = (const float*)d_in[13]; const float* e2_b1 = (const float*)d_in[14];
    const float* e2_W2 = (const float*)d_in[15]; const float* e2_b2 = (const float*)d_in[16];
    const float* gWih  = (const float*)d_in[17]; const float* gWhh  = (const float*)d_in[18];
    const float* gbih  = (const float*)d_in[19]; const float* gbhh  = (const float*)d_in[20];
    float* outp = (float*)d_out;

    char* ws = (char*)d_ws;
    float*  Wt   = (float*)(ws + WT_OFF);
    float*  h0b  = (float*)(ws + H0_OFF);
    float*  h1b  = (float*)(ws + H1_OFF);
    float4* Wpk4 = (float4*)(ws + W4_OFF);
    float2* Wpk2 = (float2*)(ws + W2_OFF);
    float*  ls0  = (float*)(ws + LS0_OFF);
    float*  bs0  = (float*)(ws + BS0_OFF);
    float*  ls1  = (float*)(ws + LS1_OFF);
    float*  bs1  = (float*)(ws + BS1_OFF);
    int*    cnt  = (int*)  (ws + CNT_OFF);
    int*    blkE = (int*)  (ws + EPK_OFF);
    float*  W2T1 = (float*)(ws + W2T1_OFF);
    float*  W2T2 = (float*)(ws + W2T2_OFF);
    float*  PT   = (float*)(ws + PT_OFF);

    // K0: transposes + GRU pack + cnt zero (replaces the old memset dispatch)
    pre_kernel<<<38, 256, 0, stream>>>(
        e1_W2, e2_W2, proj_W, gWih, gWhh, W2T1, W2T2, PT, Wpk4, Wpk2, cnt);

    setup_kernel<<<(TA_TOTAL + 255) / 256, 256, 0, stream>>>(
        node_ids, srcp, dstp, edge_ids, node_table, edge_table, PT, proj_b,
        attn_w, e1_W1, e1_b1, e1_b2, e2_W1, e2_b1, e2_b2, W2T1, W2T2,
        Wt, h0b, ls0, bs0, cnt, blkE);

    float* hc = h0b;  float* hn = h1b;
    float* lc = ls0;  float* bc = bs0;
    float* ln = ls1;  float* bn = bs1;
    for (int step = 0; step < 3; ++step) {
        int last = (step == 2);
        float* op = last ? outp : hn;
        mp_kernel<<<NBLK, 256, 0, stream>>>(
            cnt, blkE, hc, Wt, attn_w, Wpk4, Wpk2, gbih, gbhh,
            lc, bc, ln, bn, op, last);
        float* tf;
        tf = hc; hc = hn; hn = tf;
        tf = lc; lc = ln; ln = tf;
        tf = bc; bc = bn; bn = tf;
    }
}